// Round 1
// baseline (905.060 us; speedup 1.0000x reference)
//
#include <hip/hip_runtime.h>
#include <hip/hip_bf16.h>

// LoRA forward on MI355X:
//   out = x @ W^T + 2.0 * (x @ A^T) @ B^T
// Strategy: W_eff = W + 2*B@A (bf16), xb = bf16(x); single bf16 MFMA GEMM
// C[M,N] = xb[M,K] @ W_eff[N,K]^T  (B^T layout, m97 128x128 structure).

typedef __bf16 bf16;
typedef bf16 bf16x8 __attribute__((ext_vector_type(8)));
typedef float f32x4 __attribute__((ext_vector_type(4)));

typedef __attribute__((address_space(1))) const void* as1cv;
typedef __attribute__((address_space(3))) void* as3v;

constexpr int Mdim = 16384;
constexpr int Ndim = 4096;
constexpr int Kdim = 4096;
constexpr int Rdim = 8;
constexpr float kScale = 2.0f;  // lora_alpha / r = 16/8

__device__ __forceinline__ unsigned short f2bf(float f) {
  union { float f; unsigned u; } v; v.f = f;
  unsigned u = v.u;
  u += 0x7fffu + ((u >> 16) & 1u);   // round-to-nearest-even
  return (unsigned short)(u >> 16);
}

// ---------------- Kernel 1: cast x (f32) -> xb (bf16) ----------------
__global__ void cast_x_kernel(const float4* __restrict__ x4,
                              ushort4* __restrict__ o4, int n4) {
  int i = blockIdx.x * blockDim.x + threadIdx.x;
  int stride = gridDim.x * blockDim.x;
  for (; i < n4; i += stride) {
    float4 v = x4[i];
    ushort4 o;
    o.x = f2bf(v.x); o.y = f2bf(v.y); o.z = f2bf(v.z); o.w = f2bf(v.w);
    o4[i] = o;
  }
}

// ---------------- Kernel 2: W_eff = W + 2*(B@A), cast to bf16 --------
// One thread -> 8 consecutive k of one row n. K/8 = 512 threads per row.
__global__ void make_weff_kernel(const float* __restrict__ W,
                                 const float* __restrict__ A,
                                 const float* __restrict__ Bm,
                                 ushort* __restrict__ weff) {
  int tid = blockIdx.x * blockDim.x + threadIdx.x;
  int kc = tid & 511;       // K/8 = 512
  int n = tid >> 9;
  if (n >= Ndim) return;

  const float* wp = W + (long)n * Kdim + kc * 8;
  float4 w0 = *(const float4*)(wp);
  float4 w1 = *(const float4*)(wp + 4);

  float4 b0 = *(const float4*)(Bm + n * Rdim);
  float4 b1 = *(const float4*)(Bm + n * Rdim + 4);
  float bs[8] = {b0.x, b0.y, b0.z, b0.w, b1.x, b1.y, b1.z, b1.w};

  float l[8] = {0.f, 0.f, 0.f, 0.f, 0.f, 0.f, 0.f, 0.f};
#pragma unroll
  for (int r = 0; r < Rdim; ++r) {
    const float* ap = A + (long)r * Kdim + kc * 8;
    float4 a0 = *(const float4*)(ap);
    float4 a1 = *(const float4*)(ap + 4);
    l[0] += bs[r] * a0.x; l[1] += bs[r] * a0.y;
    l[2] += bs[r] * a0.z; l[3] += bs[r] * a0.w;
    l[4] += bs[r] * a1.x; l[5] += bs[r] * a1.y;
    l[6] += bs[r] * a1.z; l[7] += bs[r] * a1.w;
  }

  float o[8] = {w0.x + kScale * l[0], w0.y + kScale * l[1],
                w0.z + kScale * l[2], w0.w + kScale * l[3],
                w1.x + kScale * l[4], w1.y + kScale * l[5],
                w1.z + kScale * l[6], w1.w + kScale * l[7]};
  uint4 pk;
  pk.x = (unsigned)f2bf(o[0]) | ((unsigned)f2bf(o[1]) << 16);
  pk.y = (unsigned)f2bf(o[2]) | ((unsigned)f2bf(o[3]) << 16);
  pk.z = (unsigned)f2bf(o[4]) | ((unsigned)f2bf(o[5]) << 16);
  pk.w = (unsigned)f2bf(o[6]) | ((unsigned)f2bf(o[7]) << 16);
  *(uint4*)(weff + (long)n * Kdim + kc * 8) = pk;
}

// ---------------- Kernel 3: C = xb @ W_eff^T (bf16 MFMA) -------------
// m97 structure: 128x128 tile, BK=64, 256 threads (4 waves, 2x2),
// each wave computes 64x64 = 4x4 frags of 16x16x32 MFMA.
#define BM 128
#define BN 128
#define BK 64

__global__ __launch_bounds__(256) void gemm_bt(const bf16* __restrict__ Xb,
                                               const bf16* __restrict__ Wb,
                                               float* __restrict__ C) {
  __shared__ bf16 lA[BM * BK];  // 16 KB
  __shared__ bf16 lB[BN * BK];  // 16 KB

  const int t = threadIdx.x;
  const int lane = t & 63;
  const int wave = t >> 6;
  const int wr = wave >> 1;
  const int wc = wave & 1;
  const int fr = lane & 15;   // row (A) / col (B) within fragment
  const int fq = lane >> 4;   // k-chunk selector; also C row group

  const int brow = blockIdx.y * BM;
  const int bcol = blockIdx.x * BN;

  // staging decomposition: thread t covers 16B chunk (t&7) of row (t>>3);
  // each issue q advances 32 rows. LDS dst is linear base + lane*16. ✓
  const int rS = t >> 3;  // 0..31
  const int kS = t & 7;   // 0..7

  const bf16* gA = Xb + (long)(brow + rS) * Kdim + kS * 8;
  const bf16* gB = Wb + (long)(bcol + rS) * Kdim + kS * 8;
  bf16* sA = &lA[rS * BK + kS * 8];
  bf16* sB = &lB[rS * BK + kS * 8];

  f32x4 acc[4][4];
#pragma unroll
  for (int m = 0; m < 4; ++m)
#pragma unroll
    for (int n = 0; n < 4; ++n)
      acc[m][n] = (f32x4){0.f, 0.f, 0.f, 0.f};

  const bf16* rdA = &lA[(wr * 64 + fr) * BK + fq * 8];
  const bf16* rdB = &lB[(wc * 64 + fr) * BK + fq * 8];

  for (int k0 = 0; k0 < Kdim; k0 += BK) {
    __syncthreads();  // prev compute done before overwriting LDS
#pragma unroll
    for (int q = 0; q < 4; ++q) {
      __builtin_amdgcn_global_load_lds((as1cv)(gA + (long)q * 32 * Kdim + k0),
                                       (as3v)(sA + q * 32 * BK), 16, 0, 0);
      __builtin_amdgcn_global_load_lds((as1cv)(gB + (long)q * 32 * Kdim + k0),
                                       (as3v)(sB + q * 32 * BK), 16, 0, 0);
    }
    __syncthreads();  // compiler drains vmcnt(0) before s_barrier

#pragma unroll
    for (int kk = 0; kk < 2; ++kk) {
      bf16x8 af[4], bf_[4];
#pragma unroll
      for (int m = 0; m < 4; ++m)
        af[m] = *(const bf16x8*)(rdA + m * 16 * BK + kk * 32);
#pragma unroll
      for (int n = 0; n < 4; ++n)
        bf_[n] = *(const bf16x8*)(rdB + n * 16 * BK + kk * 32);
#pragma unroll
      for (int m = 0; m < 4; ++m)
#pragma unroll
        for (int n = 0; n < 4; ++n)
          acc[m][n] = __builtin_amdgcn_mfma_f32_16x16x32_bf16(
              af[m], bf_[n], acc[m][n], 0, 0, 0);
    }
  }

  // C/D layout (m89-verified): col = lane&15, row = (lane>>4)*4 + reg
  const int crow0 = brow + wr * 64 + fq * 4;
  const int ccol0 = bcol + wc * 64 + fr;
#pragma unroll
  for (int m = 0; m < 4; ++m) {
#pragma unroll
    for (int n = 0; n < 4; ++n) {
      f32x4 v = acc[m][n];
      long base = (long)(crow0 + m * 16) * Ndim + (ccol0 + n * 16);
      C[base] = v[0];
      C[base + Ndim] = v[1];
      C[base + 2 * (long)Ndim] = v[2];
      C[base + 3 * (long)Ndim] = v[3];
    }
  }
}

extern "C" void kernel_launch(void* const* d_in, const int* in_sizes, int n_in,
                              void* d_out, int out_size, void* d_ws,
                              size_t ws_size, hipStream_t stream) {
  const float* x = (const float*)d_in[0];       // [4,4096,4096] -> [M,K]
  const float* W = (const float*)d_in[1];       // [N,K]
  const float* lA = (const float*)d_in[2];      // [R,K]
  const float* lB = (const float*)d_in[3];      // [N,R]
  float* out = (float*)d_out;                   // [M,N] f32

  ushort* xb = (ushort*)d_ws;                          // M*K bf16 = 134 MB
  ushort* weff = xb + (size_t)Mdim * Kdim;             // N*K bf16 = 33.5 MB

  cast_x_kernel<<<2048, 256, 0, stream>>>((const float4*)x, (ushort4*)xb,
                                          (Mdim * Kdim) / 4);
  make_weff_kernel<<<(Ndim * (Kdim / 8)) / 256, 256, 0, stream>>>(W, lA, lB,
                                                                  weff);
  dim3 grid(Ndim / BN, Mdim / BM);  // consecutive blocks share the A panel
  gemm_bt<<<grid, 256, 0, stream>>>((const bf16*)xb, (const bf16*)weff, out);
}

// Round 2
// 649.227 us; speedup vs baseline: 1.3941x; 1.3941x over previous
//
#include <hip/hip_runtime.h>
#include <hip/hip_bf16.h>

// LoRA forward on MI355X:
//   out = x @ W^T + 2.0 * (x @ A^T) @ B^T
// W_eff = W + 2*(B@A) in bf16, xb = bf16(x); one bf16 MFMA GEMM
// C[16384,4096] = xb @ W_eff^T using the 256x256 8-phase schedule
// (T2 chunk-XOR swizzle + T3/T4 counted-vmcnt pipeline + T5 setprio).

typedef __bf16 bf16;
typedef bf16 bf16x8 __attribute__((ext_vector_type(8)));
typedef float f32x4 __attribute__((ext_vector_type(4)));

typedef __attribute__((address_space(1))) const void* as1cv;
typedef __attribute__((address_space(3))) void* as3v;

constexpr int Mdim = 16384;
constexpr int Ndim = 4096;
constexpr int Kdim = 4096;
constexpr int Rdim = 8;
constexpr float kScale = 2.0f;  // lora_alpha / r = 16/8

__device__ __forceinline__ unsigned short f2bf(float f) {
  union { float f; unsigned u; } v; v.f = f;
  unsigned u = v.u;
  u += 0x7fffu + ((u >> 16) & 1u);   // round-to-nearest-even
  return (unsigned short)(u >> 16);
}

// ---------------- Kernel 1: cast x (f32) -> xb (bf16) ----------------
__global__ void cast_x_kernel(const float4* __restrict__ x4,
                              ushort4* __restrict__ o4, int n4) {
  int i = blockIdx.x * blockDim.x + threadIdx.x;
  int stride = gridDim.x * blockDim.x;
  for (; i < n4; i += stride) {
    float4 v = x4[i];
    ushort4 o;
    o.x = f2bf(v.x); o.y = f2bf(v.y); o.z = f2bf(v.z); o.w = f2bf(v.w);
    o4[i] = o;
  }
}

// ---------------- Kernel 2: W_eff = W + 2*(B@A), cast to bf16 --------
__global__ void make_weff_kernel(const float* __restrict__ W,
                                 const float* __restrict__ A,
                                 const float* __restrict__ Bm,
                                 ushort* __restrict__ weff) {
  int tid = blockIdx.x * blockDim.x + threadIdx.x;
  int kc = tid & 511;       // K/8 = 512
  int n = tid >> 9;
  if (n >= Ndim) return;

  const float* wp = W + (long)n * Kdim + kc * 8;
  float4 w0 = *(const float4*)(wp);
  float4 w1 = *(const float4*)(wp + 4);

  float4 b0 = *(const float4*)(Bm + n * Rdim);
  float4 b1 = *(const float4*)(Bm + n * Rdim + 4);
  float bs[8] = {b0.x, b0.y, b0.z, b0.w, b1.x, b1.y, b1.z, b1.w};

  float l[8] = {0.f, 0.f, 0.f, 0.f, 0.f, 0.f, 0.f, 0.f};
#pragma unroll
  for (int r = 0; r < Rdim; ++r) {
    const float* ap = A + (long)r * Kdim + kc * 8;
    float4 a0 = *(const float4*)(ap);
    float4 a1 = *(const float4*)(ap + 4);
    l[0] += bs[r] * a0.x; l[1] += bs[r] * a0.y;
    l[2] += bs[r] * a0.z; l[3] += bs[r] * a0.w;
    l[4] += bs[r] * a1.x; l[5] += bs[r] * a1.y;
    l[6] += bs[r] * a1.z; l[7] += bs[r] * a1.w;
  }

  float o[8] = {w0.x + kScale * l[0], w0.y + kScale * l[1],
                w0.z + kScale * l[2], w0.w + kScale * l[3],
                w1.x + kScale * l[4], w1.y + kScale * l[5],
                w1.z + kScale * l[6], w1.w + kScale * l[7]};
  uint4 pk;
  pk.x = (unsigned)f2bf(o[0]) | ((unsigned)f2bf(o[1]) << 16);
  pk.y = (unsigned)f2bf(o[2]) | ((unsigned)f2bf(o[3]) << 16);
  pk.z = (unsigned)f2bf(o[4]) | ((unsigned)f2bf(o[5]) << 16);
  pk.w = (unsigned)f2bf(o[6]) | ((unsigned)f2bf(o[7]) << 16);
  *(uint4*)(weff + (long)n * Kdim + kc * 8) = pk;
}

// ---------------- Kernel 3: C = xb @ W_eff^T, 256^2 8-phase ----------
#define BM 256
#define BN 256
#define BK 64
#define NT (Kdim / BK)   // 64 K-tiles

#define SCHED0 __builtin_amdgcn_sched_barrier(0)
#define BARRIER do { SCHED0; __builtin_amdgcn_s_barrier(); SCHED0; } while (0)
#define VMCNT(n) asm volatile("s_waitcnt vmcnt(" #n ")" ::: "memory")

__global__ __launch_bounds__(512, 2) void gemm256(const bf16* __restrict__ Xb,
                                                  const bf16* __restrict__ Wb,
                                                  float* __restrict__ C) {
  // [dbuf][A/B][256 rows][64 cols] bf16 = 128 KiB
  __shared__ bf16 lds[2][2][BM * BK];

  const int tid = threadIdx.x;
  const int lane = tid & 63;
  const int wave = tid >> 6;
  const int wr = wave >> 2;    // 0..1  (M half)
  const int wc = wave & 3;     // 0..3  (N quarter)
  const int fr = lane & 15;
  const int fq = lane >> 4;

  // XCD-aware swizzle: 1024 blocks, 8 XCDs, 128 contiguous per XCD
  const int wg = blockIdx.x;
  const int swz = (wg & 7) * 128 + (wg >> 3);
  const int by = swz >> 4;     // 0..63  (M block)
  const int bx = swz & 15;     // 0..15  (N block)
  const int brow = by * BM;
  const int bcol = bx * BN;

  // ---- staging geometry: chunk (16B) q = issue*512 + tid covers
  // row = q>>3, slot = q&7; logical chunk cg = slot ^ (row&7) (T2 involution)
  const int rq = tid >> 3;     // 0..63
  const int cs = tid & 7;
  const int cg = cs ^ (rq & 7);
  const bf16* pA = Xb + (long)(brow + rq) * Kdim + cg * 8;
  const bf16* pB = Wb + (long)(bcol + rq) * Kdim + cg * 8;

#define STAGE_HALF(buf, mat, pX, kt, h)                                       \
  {                                                                           \
    const bf16* s_ = (pX) + (long)((h) * 128) * Kdim + ((kt) & (NT - 1)) * 64;\
    __builtin_amdgcn_global_load_lds((as1cv)(s_),                             \
        (as3v)(&lds[buf][mat][(h) * 128 * BK] + tid * 8), 16, 0, 0);          \
    __builtin_amdgcn_global_load_lds((as1cv)(s_ + 64 * (long)Kdim),           \
        (as3v)(&lds[buf][mat][((h) * 128 + 64) * BK] + tid * 8), 16, 0, 0);   \
  }

  // ---- frag-read bases (swizzled): key = fr&7, chunk offsets per kk
  const bf16* aB[2] = {&lds[0][0][(wr * 128 + fr) * BK],
                       &lds[1][0][(wr * 128 + fr) * BK]};
  const bf16* bB[2] = {&lds[0][1][(wc * 64 + fr) * BK],
                       &lds[1][1][(wc * 64 + fr) * BK]};
  const int cofs0 = ((fq + 0) ^ (fr & 7)) * 8;   // kk=0 chunk, elements
  const int cofs1 = ((fq + 4) ^ (fr & 7)) * 8;   // kk=1 chunk

  f32x4 acc[8][4];
#pragma unroll
  for (int m = 0; m < 8; ++m)
#pragma unroll
    for (int n = 0; n < 4; ++n)
      acc[m][n] = (f32x4){0.f, 0.f, 0.f, 0.f};

  bf16x8 aF[4][2];        // A frags for current mh
  bf16x8 bF[2][2][2];     // [nh][n2][kk], cached across phases

#define LDA(buf, mh)                                                          \
  { _Pragma("unroll") for (int m4 = 0; m4 < 4; ++m4) {                        \
      aF[m4][0] = *(const bf16x8*)(aB[buf] + ((mh) * 64 + m4 * 16) * BK + cofs0); \
      aF[m4][1] = *(const bf16x8*)(aB[buf] + ((mh) * 64 + m4 * 16) * BK + cofs1); \
  } }
#define LDB(buf, nh)                                                          \
  { _Pragma("unroll") for (int n2 = 0; n2 < 2; ++n2) {                        \
      bF[nh][n2][0] = *(const bf16x8*)(bB[buf] + ((nh) * 2 + n2) * 16 * BK + cofs0); \
      bF[nh][n2][1] = *(const bf16x8*)(bB[buf] + ((nh) * 2 + n2) * 16 * BK + cofs1); \
  } }
#define MFMAQ(mh, nh)                                                         \
  { __builtin_amdgcn_s_setprio(1);                                            \
    _Pragma("unroll") for (int m4 = 0; m4 < 4; ++m4)                          \
    _Pragma("unroll") for (int n2 = 0; n2 < 2; ++n2)                          \
    _Pragma("unroll") for (int kk = 0; kk < 2; ++kk)                          \
      acc[(mh) * 4 + m4][(nh) * 2 + n2] =                                     \
          __builtin_amdgcn_mfma_f32_16x16x32_bf16(                            \
              aF[m4][kk], bF[nh][n2][kk], acc[(mh) * 4 + m4][(nh) * 2 + n2],  \
              0, 0, 0);                                                       \
    __builtin_amdgcn_s_setprio(0); }

  // One K-tile = 4 phases. Half-tiles of tile t+1: H3 staged in P0;
  // H0..H2 of tile t+2 staged after the final barrier (freed buffer).
  // Single counted vmcnt(6) per tile (3 half-tiles in flight).
#define TILE(bc, bn, ktn, ktn2)                                               \
  {                                                                           \
    /* P0 */                                                                  \
    LDA(bc, 0); LDB(bc, 0);                                                   \
    STAGE_HALF(bn, 1, pB, ktn, 1);        /* H3 = B,h1 of tile ktn */         \
    BARRIER;                                                                  \
    MFMAQ(0, 0); BARRIER;                                                     \
    /* P1 */                                                                  \
    LDB(bc, 1); BARRIER;                                                      \
    MFMAQ(0, 1); BARRIER;                                                     \
    /* P2 */                                                                  \
    LDA(bc, 1); BARRIER;                                                      \
    MFMAQ(1, 0); BARRIER;                                                     \
    /* P3 */                                                                  \
    MFMAQ(1, 1); BARRIER;   /* all waves done reading buf bc */               \
    STAGE_HALF(bc, 0, pA, ktn2, 0);       /* H0 = A,h0 of tile ktn2 */        \
    STAGE_HALF(bc, 0, pA, ktn2, 1);       /* H1 = A,h1 */                     \
    STAGE_HALF(bc, 1, pB, ktn2, 0);       /* H2 = B,h0 */                     \
    VMCNT(6);               /* tile ktn fully landed; 6 newest in flight */   \
    BARRIER;                                                                  \
  }

  // ---- prologue: tile0 complete + 3 half-tiles of tile1
  STAGE_HALF(0, 0, pA, 0, 0);
  STAGE_HALF(0, 0, pA, 0, 1);
  STAGE_HALF(0, 1, pB, 0, 0);
  STAGE_HALF(0, 1, pB, 0, 1);
  STAGE_HALF(1, 0, pA, 1, 0);
  STAGE_HALF(1, 0, pA, 1, 1);
  STAGE_HALF(1, 1, pB, 1, 0);
  VMCNT(6);
  BARRIER;

  int kt = 0;
#pragma unroll 1
  for (int it = 0; it < NT / 2; ++it, kt += 2) {
    TILE(0, 1, kt + 1, kt + 2);   // compute tile kt   (wrap-dummies at tail
    TILE(1, 0, kt + 2, kt + 3);   // compute tile kt+1  target dead buffers)
  }
  VMCNT(0);  // drain dummy tail loads before reusing nothing; cheap, once

  // ---- epilogue: C/D layout col=lane&15, row=(lane>>4)*4+reg
  const int crow = brow + wr * 128 + fq * 4;
  const int ccol = bcol + wc * 64 + fr;
#pragma unroll
  for (int m = 0; m < 8; ++m) {
#pragma unroll
    for (int n = 0; n < 4; ++n) {
      f32x4 v = acc[m][n];
      long base = (long)(crow + m * 16) * Ndim + (ccol + n * 16);
      C[base] = v[0];
      C[base + Ndim] = v[1];
      C[base + 2 * (long)Ndim] = v[2];
      C[base + 3 * (long)Ndim] = v[3];
    }
  }
}

extern "C" void kernel_launch(void* const* d_in, const int* in_sizes, int n_in,
                              void* d_out, int out_size, void* d_ws,
                              size_t ws_size, hipStream_t stream) {
  const float* x = (const float*)d_in[0];       // [4,4096,4096] -> [M,K]
  const float* W = (const float*)d_in[1];       // [N,K]
  const float* lA = (const float*)d_in[2];      // [R,K]
  const float* lB = (const float*)d_in[3];      // [N,R]
  float* out = (float*)d_out;                   // [M,N] f32

  ushort* xb = (ushort*)d_ws;                          // M*K bf16 = 134 MB
  ushort* weff = xb + (size_t)Mdim * Kdim;             // N*K bf16 = 33.5 MB

  cast_x_kernel<<<2048, 256, 0, stream>>>((const float4*)x, (ushort4*)xb,
                                          (Mdim * Kdim) / 4);
  make_weff_kernel<<<(Ndim * (Kdim / 8)) / 256, 256, 0, stream>>>(W, lA, lB,
                                                                  weff);
  dim3 grid((Mdim / BM) * (Ndim / BN));  // 64*16 = 1024 blocks
  gemm256<<<grid, 512, 0, stream>>>((const bf16*)xb, (const bf16*)weff, out);
}

// Round 3
// 571.215 us; speedup vs baseline: 1.5844x; 1.1366x over previous
//
#include <hip/hip_runtime.h>
#include <hip/hip_bf16.h>

// LoRA forward on MI355X:
//   out = x @ W^T + 2.0 * (x @ A^T) @ B^T
// W_eff = W + 2*(B@A) in bf16, xb = bf16(x); one bf16 MFMA GEMM
// C[16384,4096] = xb @ W_eff^T, 256x256 8-phase schedule, template-faithful:
// 1 half-tile stage per phase (phase-consumption-ordered halves), vmcnt(6)
// once per K-tile, lgkm pacing, setprio, chunk-XOR swizzle (0 conflicts).

typedef __bf16 bf16;
typedef bf16 bf16x8 __attribute__((ext_vector_type(8)));
typedef float f32x4 __attribute__((ext_vector_type(4)));

typedef __attribute__((address_space(1))) const void* as1cv;
typedef __attribute__((address_space(3))) void* as3v;

constexpr int Mdim = 16384;
constexpr int Ndim = 4096;
constexpr int Kdim = 4096;
constexpr int Rdim = 8;
constexpr float kScale = 2.0f;  // lora_alpha / r = 16/8

__device__ __forceinline__ unsigned short f2bf(float f) {
  union { float f; unsigned u; } v; v.f = f;
  unsigned u = v.u;
  u += 0x7fffu + ((u >> 16) & 1u);   // round-to-nearest-even
  return (unsigned short)(u >> 16);
}

// ---------------- Kernel 1: cast x (f32) -> xb (bf16) ----------------
__global__ void cast_x_kernel(const float4* __restrict__ x4,
                              ushort4* __restrict__ o4, int n4) {
  int i = blockIdx.x * blockDim.x + threadIdx.x;
  int stride = gridDim.x * blockDim.x;
  for (; i < n4; i += stride) {
    float4 v = x4[i];
    ushort4 o;
    o.x = f2bf(v.x); o.y = f2bf(v.y); o.z = f2bf(v.z); o.w = f2bf(v.w);
    o4[i] = o;
  }
}

// ---------------- Kernel 2: W_eff = W + 2*(B@A), cast to bf16 --------
__global__ void make_weff_kernel(const float* __restrict__ W,
                                 const float* __restrict__ A,
                                 const float* __restrict__ Bm,
                                 ushort* __restrict__ weff) {
  int tid = blockIdx.x * blockDim.x + threadIdx.x;
  int kc = tid & 511;       // K/8 = 512
  int n = tid >> 9;
  if (n >= Ndim) return;

  const float* wp = W + (long)n * Kdim + kc * 8;
  float4 w0 = *(const float4*)(wp);
  float4 w1 = *(const float4*)(wp + 4);

  float4 b0 = *(const float4*)(Bm + n * Rdim);
  float4 b1 = *(const float4*)(Bm + n * Rdim + 4);
  float bs[8] = {b0.x, b0.y, b0.z, b0.w, b1.x, b1.y, b1.z, b1.w};

  float l[8] = {0.f, 0.f, 0.f, 0.f, 0.f, 0.f, 0.f, 0.f};
#pragma unroll
  for (int r = 0; r < Rdim; ++r) {
    const float* ap = A + (long)r * Kdim + kc * 8;
    float4 a0 = *(const float4*)(ap);
    float4 a1 = *(const float4*)(ap + 4);
    l[0] += bs[r] * a0.x; l[1] += bs[r] * a0.y;
    l[2] += bs[r] * a0.z; l[3] += bs[r] * a0.w;
    l[4] += bs[r] * a1.x; l[5] += bs[r] * a1.y;
    l[6] += bs[r] * a1.z; l[7] += bs[r] * a1.w;
  }

  float o[8] = {w0.x + kScale * l[0], w0.y + kScale * l[1],
                w0.z + kScale * l[2], w0.w + kScale * l[3],
                w1.x + kScale * l[4], w1.y + kScale * l[5],
                w1.z + kScale * l[6], w1.w + kScale * l[7]};
  uint4 pk;
  pk.x = (unsigned)f2bf(o[0]) | ((unsigned)f2bf(o[1]) << 16);
  pk.y = (unsigned)f2bf(o[2]) | ((unsigned)f2bf(o[3]) << 16);
  pk.z = (unsigned)f2bf(o[4]) | ((unsigned)f2bf(o[5]) << 16);
  pk.w = (unsigned)f2bf(o[6]) | ((unsigned)f2bf(o[7]) << 16);
  *(uint4*)(weff + (long)n * Kdim + kc * 8) = pk;
}

// ---------------- Kernel 3: C = xb @ W_eff^T, 256^2 8-phase ----------
#define BM 256
#define BN 256
#define BK 64
#define NT (Kdim / BK)   // 64 K-tiles

#define SCHED0 __builtin_amdgcn_sched_barrier(0)
#define BAR do { SCHED0; __builtin_amdgcn_s_barrier(); SCHED0; } while (0)
#define VMCNT(n) do { asm volatile("s_waitcnt vmcnt(" #n ")" ::: "memory"); SCHED0; } while (0)
#define LGKM(n) do { asm volatile("s_waitcnt lgkmcnt(" #n ")" ::: "memory"); SCHED0; } while (0)
#define GLOAD(src, dst) \
  __builtin_amdgcn_global_load_lds((as1cv)(src), (as3v)(dst), 16, 0, 0)

// Halves are defined by CONSUMPTION quadrant, not contiguous rows:
//   A half mh: rows { wr*128 + mh*64 + [0,64) : wr=0,1 }
//     storage s = (m4*16+fr) + wr*64,  global row = (s&63) + (s>>6)*128 + mh*64
//   B half nh: rows { wc*64 + nh*32 + [0,32) : wc=0..3 }
//     storage s = (n2*16+fr) + wc*32,  global row = (s&31) + (s>>5)*64 + nh*32
// Chunk-XOR swizzle: stored 16B chunk cs of row s holds logical chunk cs^(s&7).

__global__ __launch_bounds__(512, 2) void gemm256(const bf16* __restrict__ Xb,
                                                  const bf16* __restrict__ Wb,
                                                  float* __restrict__ C) {
  __shared__ bf16 lds[2][2][2][128 * 64];  // [dbuf][A/B][half][8192] = 128 KiB

  const int tid = threadIdx.x;
  const int lane = tid & 63;
  const int wave = tid >> 6;
  const int wr = wave >> 2;    // 0..1  (M half)
  const int wc = wave & 3;     // 0..3  (N quarter)
  const int fr = lane & 15;
  const int fq = lane >> 4;

  // XCD-aware bijective swizzle: 1024 blocks, 8 XCDs, 128 contiguous per XCD
  const int wg = blockIdx.x;
  const int swz = (wg & 7) * 128 + (wg >> 3);
  const int by = swz >> 4;     // 0..63  (M block)
  const int bx = swz & 15;     // 0..15  (N block)
  const int brow = by * BM;
  const int bcol = bx * BN;

  // ---- staging pointers (per thread): storage row sLow, swizzled chunk
  const int sLow = tid >> 3;                       // 0..63
  const int cg = (tid & 7) ^ (sLow & 7);           // logical chunk (involution)
  const bf16* pA = Xb + (long)(brow + sLow) * Kdim + cg * 8;
  const bf16* pB =
      Wb + (long)(bcol + (sLow & 31) + (sLow >> 5) * 64) * Kdim + cg * 8;

#define STAGE_A(buf, h, kt) do {                                              \
    const bf16* s_ = pA + (long)((h) * 64) * Kdim + (((kt) & (NT - 1)) * 64); \
    GLOAD(s_, &lds[buf][0][h][0] + tid * 8);                                  \
    GLOAD(s_ + (long)128 * Kdim, &lds[buf][0][h][4096] + tid * 8);            \
  } while (0)
#define STAGE_B(buf, h, kt) do {                                              \
    const bf16* s_ = pB + (long)((h) * 32) * Kdim + (((kt) & (NT - 1)) * 64); \
    GLOAD(s_, &lds[buf][1][h][0] + tid * 8);                                  \
    GLOAD(s_ + (long)128 * Kdim, &lds[buf][1][h][4096] + tid * 8);            \
  } while (0)

  // ---- frag-read bases (swizzled)
  const bf16* aBs[2] = {&lds[0][0][0][(wr * 64 + fr) * 64],
                        &lds[1][0][0][(wr * 64 + fr) * 64]};
  const bf16* bBs[2] = {&lds[0][1][0][(wc * 32 + fr) * 64],
                        &lds[1][1][0][(wc * 32 + fr) * 64]};
  const int cofs0 = ((fq + 0) ^ (fr & 7)) * 8;   // kk=0 chunk
  const int cofs1 = ((fq + 4) ^ (fr & 7)) * 8;   // kk=1 chunk

  f32x4 acc[8][4];
#pragma unroll
  for (int m = 0; m < 8; ++m)
#pragma unroll
    for (int n = 0; n < 4; ++n)
      acc[m][n] = (f32x4){0.f, 0.f, 0.f, 0.f};

  bf16x8 aF[4][2];     // A frags, current mh (8 ds_read_b128)
  bf16x8 bF[2][2][2];  // [nh][n2][kk], both nh cached per tile

#define LDA(buf, mh)                                                          \
  { _Pragma("unroll") for (int m4 = 0; m4 < 4; ++m4) {                        \
      aF[m4][0] = *(const bf16x8*)(aBs[buf] + (mh) * 8192 + m4 * 1024 + cofs0); \
      aF[m4][1] = *(const bf16x8*)(aBs[buf] + (mh) * 8192 + m4 * 1024 + cofs1); \
  } }
#define LDB(buf, nh)                                                          \
  { _Pragma("unroll") for (int n2 = 0; n2 < 2; ++n2) {                        \
      bF[nh][n2][0] = *(const bf16x8*)(bBs[buf] + (nh) * 8192 + n2 * 1024 + cofs0); \
      bF[nh][n2][1] = *(const bf16x8*)(bBs[buf] + (nh) * 8192 + n2 * 1024 + cofs1); \
  } }
#define MFMAQ(mh, nh)                                                         \
  { __builtin_amdgcn_s_setprio(1);                                            \
    _Pragma("unroll") for (int m4 = 0; m4 < 4; ++m4)                          \
    _Pragma("unroll") for (int n2 = 0; n2 < 2; ++n2)                          \
    _Pragma("unroll") for (int kk = 0; kk < 2; ++kk)                          \
      acc[(mh) * 4 + m4][(nh) * 2 + n2] =                                     \
          __builtin_amdgcn_mfma_f32_16x16x32_bf16(                            \
              aF[m4][kk], bF[nh][n2][kk], acc[(mh) * 4 + m4][(nh) * 2 + n2],  \
              0, 0, 0);                                                       \
    __builtin_amdgcn_s_setprio(0); }

  // One K-tile = 4 phases, quadrant order (0,0),(0,1),(1,1),(1,0).
  // Slot last-read: A-h0@P0, B-h0@P0, B-h1@P1, A-h1@P2.
  // Stage schedule (1 half/phase, each >=1 barrier after its slot's last read):
  //   P0: A-h1(t+1)->bn   P1: A-h0(t+2)->bc   P2: B-h0(t+2)->bc
  //   P3: B-h1(t+2)->bc, then vmcnt(6): 3 half-tiles (6 loads) stay in flight.
#define TILE(bc, bn, t) do {                                                  \
    /* P0: (0,0) */                                                           \
    LDA(bc, 0); LDB(bc, 0);                                                   \
    STAGE_A(bn, 1, (t) + 1);                                                  \
    LGKM(8); BAR; LGKM(0);                                                    \
    MFMAQ(0, 0); BAR;                                                         \
    /* P1: (0,1) */                                                           \
    LDB(bc, 1);                                                               \
    STAGE_A(bc, 0, (t) + 2);                                                  \
    BAR; LGKM(0);                                                             \
    MFMAQ(0, 1); BAR;                                                         \
    /* P2: (1,1) */                                                           \
    LDA(bc, 1);                                                               \
    STAGE_B(bc, 0, (t) + 2);                                                  \
    BAR; LGKM(0);                                                             \
    MFMAQ(1, 1); BAR;                                                         \
    /* P3: (1,0) */                                                           \
    STAGE_B(bc, 1, (t) + 2);                                                  \
    BAR;                                                                      \
    MFMAQ(1, 0);                                                              \
    VMCNT(6); BAR;                                                            \
  } while (0)

  // ---- prologue: tile0 complete + {A-h0,B-h0,B-h1} of tile1 (deadline order)
  STAGE_A(0, 0, 0); STAGE_B(0, 0, 0); STAGE_B(0, 1, 0); STAGE_A(0, 1, 0);
  STAGE_A(1, 0, 1); STAGE_B(1, 0, 1); STAGE_B(1, 1, 1);
  VMCNT(6); BAR;

#pragma unroll 1
  for (int t = 0; t < NT; t += 2) {
    TILE(0, 1, t);        // tail wrap-dummies land only in dead slots
    TILE(1, 0, t + 1);    // (audited per-slot: staged after last read)
  }
  VMCNT(0);

  // ---- epilogue: C/D layout col=lane&15, row=(lane>>4)*4+reg
  const int crow = brow + wr * 128 + fq * 4;
  const int ccol = bcol + wc * 64 + fr;
#pragma unroll
  for (int m = 0; m < 8; ++m) {
#pragma unroll
    for (int n = 0; n < 4; ++n) {
      f32x4 v = acc[m][n];
      long base = (long)(crow + m * 16) * Ndim + (ccol + n * 16);
      C[base] = v[0];
      C[base + Ndim] = v[1];
      C[base + 2 * (long)Ndim] = v[2];
      C[base + 3 * (long)Ndim] = v[3];
    }
  }
}

extern "C" void kernel_launch(void* const* d_in, const int* in_sizes, int n_in,
                              void* d_out, int out_size, void* d_ws,
                              size_t ws_size, hipStream_t stream) {
  const float* x = (const float*)d_in[0];       // [4,4096,4096] -> [M,K]
  const float* W = (const float*)d_in[1];       // [N,K]
  const float* lA = (const float*)d_in[2];      // [R,K]
  const float* lB = (const float*)d_in[3];      // [N,R]
  float* out = (float*)d_out;                   // [M,N] f32

  ushort* xb = (ushort*)d_ws;                          // M*K bf16 = 134 MB
  ushort* weff = xb + (size_t)Mdim * Kdim;             // N*K bf16 = 33.5 MB

  cast_x_kernel<<<2048, 256, 0, stream>>>((const float4*)x, (ushort4*)xb,
                                          (Mdim * Kdim) / 4);
  make_weff_kernel<<<(Ndim * (Kdim / 8)) / 256, 256, 0, stream>>>(W, lA, lB,
                                                                  weff);
  dim3 grid((Mdim / BM) * (Ndim / BN));  // 64*16 = 1024 blocks
  gemm256<<<grid, 512, 0, stream>>>((const bf16*)xb, (const bf16*)weff, out);
}

// Round 4
// 564.831 us; speedup vs baseline: 1.6024x; 1.0113x over previous
//
#include <hip/hip_runtime.h>
#include <hip/hip_bf16.h>

// LoRA forward on MI355X:
//   out = x @ W^T + 2.0 * (x @ A^T) @ B^T
// W_eff = W + 2*(B@A) in bf16, xb = bf16(x); one bf16 MFMA GEMM
// C[16384,4096] = xb @ W_eff^T, 256x256 8-phase schedule with
// one-phase-ahead pipelined fragment reads (counted lgkm), dual vmcnt(6)
// per K-tile, chunk-XOR swizzle (0 bank conflicts), setprio on MFMA.

typedef __bf16 bf16;
typedef bf16 bf16x8 __attribute__((ext_vector_type(8)));
typedef float f32x4 __attribute__((ext_vector_type(4)));

typedef __attribute__((address_space(1))) const void* as1cv;
typedef __attribute__((address_space(3))) void* as3v;

constexpr int Mdim = 16384;
constexpr int Ndim = 4096;
constexpr int Kdim = 4096;
constexpr int Rdim = 8;
constexpr float kScale = 2.0f;  // lora_alpha / r = 16/8

__device__ __forceinline__ unsigned short f2bf(float f) {
  union { float f; unsigned u; } v; v.f = f;
  unsigned u = v.u;
  u += 0x7fffu + ((u >> 16) & 1u);   // round-to-nearest-even
  return (unsigned short)(u >> 16);
}

// ---------------- Kernel 1: cast x (f32) -> xb (bf16) ----------------
__global__ void cast_x_kernel(const float4* __restrict__ x4,
                              ushort4* __restrict__ o4, int n4) {
  int i = blockIdx.x * blockDim.x + threadIdx.x;
  int stride = gridDim.x * blockDim.x;
  for (; i < n4; i += stride) {
    float4 v = x4[i];
    ushort4 o;
    o.x = f2bf(v.x); o.y = f2bf(v.y); o.z = f2bf(v.z); o.w = f2bf(v.w);
    o4[i] = o;
  }
}

// ---------------- Kernel 2: W_eff = W + 2*(B@A), cast to bf16 --------
__global__ void make_weff_kernel(const float* __restrict__ W,
                                 const float* __restrict__ A,
                                 const float* __restrict__ Bm,
                                 ushort* __restrict__ weff) {
  int tid = blockIdx.x * blockDim.x + threadIdx.x;
  int kc = tid & 511;       // K/8 = 512
  int n = tid >> 9;
  if (n >= Ndim) return;

  const float* wp = W + (long)n * Kdim + kc * 8;
  float4 w0 = *(const float4*)(wp);
  float4 w1 = *(const float4*)(wp + 4);

  float4 b0 = *(const float4*)(Bm + n * Rdim);
  float4 b1 = *(const float4*)(Bm + n * Rdim + 4);
  float bs[8] = {b0.x, b0.y, b0.z, b0.w, b1.x, b1.y, b1.z, b1.w};

  float l[8] = {0.f, 0.f, 0.f, 0.f, 0.f, 0.f, 0.f, 0.f};
#pragma unroll
  for (int r = 0; r < Rdim; ++r) {
    const float* ap = A + (long)r * Kdim + kc * 8;
    float4 a0 = *(const float4*)(ap);
    float4 a1 = *(const float4*)(ap + 4);
    l[0] += bs[r] * a0.x; l[1] += bs[r] * a0.y;
    l[2] += bs[r] * a0.z; l[3] += bs[r] * a0.w;
    l[4] += bs[r] * a1.x; l[5] += bs[r] * a1.y;
    l[6] += bs[r] * a1.z; l[7] += bs[r] * a1.w;
  }

  float o[8] = {w0.x + kScale * l[0], w0.y + kScale * l[1],
                w0.z + kScale * l[2], w0.w + kScale * l[3],
                w1.x + kScale * l[4], w1.y + kScale * l[5],
                w1.z + kScale * l[6], w1.w + kScale * l[7]};
  uint4 pk;
  pk.x = (unsigned)f2bf(o[0]) | ((unsigned)f2bf(o[1]) << 16);
  pk.y = (unsigned)f2bf(o[2]) | ((unsigned)f2bf(o[3]) << 16);
  pk.z = (unsigned)f2bf(o[4]) | ((unsigned)f2bf(o[5]) << 16);
  pk.w = (unsigned)f2bf(o[6]) | ((unsigned)f2bf(o[7]) << 16);
  *(uint4*)(weff + (long)n * Kdim + kc * 8) = pk;
}

// ---------------- Kernel 3: C = xb @ W_eff^T, 256^2 8-phase ----------
#define BM 256
#define BN 256
#define BK 64
#define NT (Kdim / BK)   // 64 K-tiles

#define SCHED0 __builtin_amdgcn_sched_barrier(0)
#define BAR do { SCHED0; __builtin_amdgcn_s_barrier(); SCHED0; } while (0)
#define VMCNT(n) do { asm volatile("s_waitcnt vmcnt(" #n ")" ::: "memory"); SCHED0; } while (0)
#define LGKM(n) do { asm volatile("s_waitcnt lgkmcnt(" #n ")" ::: "memory"); SCHED0; } while (0)
#define GLOAD(src, dst) \
  __builtin_amdgcn_global_load_lds((as1cv)(src), (as3v)(dst), 16, 0, 0)

// Halves are defined by CONSUMPTION quadrant (phase), not contiguous rows:
//   A half mh: rows { wr*128 + mh*64 + [0,64) : wr=0,1 }
//   B half nh: rows { wc*64 + nh*32 + [0,32) : wc=0..3 }
// Chunk-XOR swizzle: stored 16B chunk cs of row s holds logical chunk cs^(s&7).

__global__ __launch_bounds__(512, 2) void gemm256(const bf16* __restrict__ Xb,
                                                  const bf16* __restrict__ Wb,
                                                  float* __restrict__ C) {
  __shared__ bf16 lds[2][2][2][128 * 64];  // [dbuf][A/B][half][8192] = 128 KiB

  const int tid = threadIdx.x;
  const int lane = tid & 63;
  const int wave = tid >> 6;
  const int wr = wave >> 2;    // 0..1  (M half)
  const int wc = wave & 3;     // 0..3  (N quarter)
  const int fr = lane & 15;
  const int fq = lane >> 4;

  // XCD-aware bijective swizzle: 1024 blocks, 8 XCDs, 128 contiguous per XCD
  const int wg = blockIdx.x;
  const int swz = (wg & 7) * 128 + (wg >> 3);
  const int by = swz >> 4;     // 0..63  (M block)
  const int bx = swz & 15;     // 0..15  (N block)
  const int brow = by * BM;
  const int bcol = bx * BN;

  // ---- staging pointers (per thread): storage row sLow, swizzled chunk
  const int sLow = tid >> 3;                       // 0..63
  const int cg = (tid & 7) ^ (sLow & 7);           // logical chunk (involution)
  const bf16* pA = Xb + (long)(brow + sLow) * Kdim + cg * 8;
  const bf16* pB =
      Wb + (long)(bcol + (sLow & 31) + (sLow >> 5) * 64) * Kdim + cg * 8;

#define STAGE_A(buf, h, kt) do {                                              \
    const bf16* s_ = pA + (long)((h) * 64) * Kdim + (((kt) & (NT - 1)) * 64); \
    GLOAD(s_, &lds[buf][0][h][0] + tid * 8);                                  \
    GLOAD(s_ + (long)128 * Kdim, &lds[buf][0][h][4096] + tid * 8);            \
  } while (0)
#define STAGE_B(buf, h, kt) do {                                              \
    const bf16* s_ = pB + (long)((h) * 32) * Kdim + (((kt) & (NT - 1)) * 64); \
    GLOAD(s_, &lds[buf][1][h][0] + tid * 8);                                  \
    GLOAD(s_ + (long)128 * Kdim, &lds[buf][1][h][4096] + tid * 8);            \
  } while (0)

  // ---- frag-read bases (swizzled)
  const bf16* aBs[2] = {&lds[0][0][0][(wr * 64 + fr) * 64],
                        &lds[1][0][0][(wr * 64 + fr) * 64]};
  const bf16* bBs[2] = {&lds[0][1][0][(wc * 32 + fr) * 64],
                        &lds[1][1][0][(wc * 32 + fr) * 64]};
  const int cofs0 = ((fq + 0) ^ (fr & 7)) * 8;   // kk=0 chunk
  const int cofs1 = ((fq + 4) ^ (fr & 7)) * 8;   // kk=1 chunk

  f32x4 acc[8][4];
#pragma unroll
  for (int m = 0; m < 8; ++m)
#pragma unroll
    for (int n = 0; n < 4; ++n)
      acc[m][n] = (f32x4){0.f, 0.f, 0.f, 0.f};

  bf16x8 aF[4][2];     // A frags, current mh (aF reused A0 -> A1 within tile)
  bf16x8 bF[2][2][2];  // [nh][n2][kk], both nh held across the tile

#define LDA(buf, mh)                                                          \
  { _Pragma("unroll") for (int m4 = 0; m4 < 4; ++m4) {                        \
      aF[m4][0] = *(const bf16x8*)(aBs[buf] + (mh) * 8192 + m4 * 1024 + cofs0); \
      aF[m4][1] = *(const bf16x8*)(aBs[buf] + (mh) * 8192 + m4 * 1024 + cofs1); \
  } }
#define LDB(buf, nh)                                                          \
  { _Pragma("unroll") for (int n2 = 0; n2 < 2; ++n2) {                        \
      bF[nh][n2][0] = *(const bf16x8*)(bBs[buf] + (nh) * 8192 + n2 * 1024 + cofs0); \
      bF[nh][n2][1] = *(const bf16x8*)(bBs[buf] + (nh) * 8192 + n2 * 1024 + cofs1); \
  } }
#define MFMAQ(mh, nh)                                                         \
  { __builtin_amdgcn_s_setprio(1);                                            \
    _Pragma("unroll") for (int m4 = 0; m4 < 4; ++m4)                          \
    _Pragma("unroll") for (int n2 = 0; n2 < 2; ++n2)                          \
    _Pragma("unroll") for (int kk = 0; kk < 2; ++kk)                          \
      acc[(mh) * 4 + m4][(nh) * 2 + n2] =                                     \
          __builtin_amdgcn_mfma_f32_16x16x32_bf16(                            \
              aF[m4][kk], bF[nh][n2][kk], acc[(mh) * 4 + m4][(nh) * 2 + n2],  \
              0, 0, 0);                                                       \
    __builtin_amdgcn_s_setprio(0); }

  // One K-tile = 4 phases, quadrants (0,0)@P0 (0,1)@P1 (1,1)@P2 (1,0)@P3.
  // Frag reads pipelined one phase ahead:
  //   P0: issue B1(t) reads (bF1 idle); MFMA(0,0) uses preloaded aF/bF0,
  //       counted LGKM(4) drains the 12 cross-tile reads from prev P3.
  //   P1: MFMA(0,1) ready (B1 had a full phase); stage A-h0(t+2).
  //   P2: issue A1(t) reads into aF (A0 dead after P1); LGKM(0); MFMA(1,1);
  //       vmcnt(6) here drains the 3 old half-tiles -> tile t+1 landed.
  //   P3: MFMA(1,0) waits on nothing; then read A0/B0(t+1) from bn (12 reads,
  //       covered until next P0's LGKM(4)); vmcnt(6) drains A-h1(t+1).
  // LDS WAR audit: every slot has >=1 full barrier between last read-wait
  // and its restage; vmcnt invariant: 6 in flight = (t+2)'s Ah0,Bh0,Bh1.
#define TILE(bc, bn, t) do {                                                  \
    /* P0 */                                                                  \
    STAGE_A(bn, 1, (t) + 1);                                                  \
    LDB(bc, 1);                                                               \
    BAR; LGKM(4);                                                             \
    MFMAQ(0, 0); BAR;                                                         \
    /* P1 */                                                                  \
    STAGE_A(bc, 0, (t) + 2);                                                  \
    BAR; LGKM(0);                                                             \
    MFMAQ(0, 1); BAR;                                                         \
    /* P2 */                                                                  \
    LDA(bc, 1);                                                               \
    STAGE_B(bc, 0, (t) + 2);                                                  \
    BAR; LGKM(0);                                                             \
    MFMAQ(1, 1);                                                              \
    VMCNT(6); BAR;                                                            \
    /* P3 */                                                                  \
    MFMAQ(1, 0);                                                              \
    LDA(bn, 0);                                                               \
    LDB(bn, 0);                                                               \
    STAGE_B(bc, 1, (t) + 2);                                                  \
    VMCNT(6); BAR;                                                            \
  } while (0)

  // ---- prologue: tile0 complete + {A-h0,B-h0,B-h1} of tile1, then pre-read
  // tile0's A0/B0 frags (12 reads) to enter steady state.
  STAGE_A(0, 0, 0); STAGE_B(0, 0, 0); STAGE_B(0, 1, 0); STAGE_A(0, 1, 0);
  STAGE_A(1, 0, 1); STAGE_B(1, 0, 1); STAGE_B(1, 1, 1);
  VMCNT(6); BAR;
  LDA(0, 0);
  LDB(0, 0);

#pragma unroll 1
  for (int t = 0; t < NT; t += 2) {
    TILE(0, 1, t);        // tail wrap-dummies land only in dead slots
    TILE(1, 0, t + 1);    // (audited per-slot: staged after last read-wait)
  }
  VMCNT(0);

  // ---- epilogue: C/D layout col=lane&15, row=(lane>>4)*4+reg
  const int crow = brow + wr * 128 + fq * 4;
  const int ccol = bcol + wc * 64 + fr;
#pragma unroll
  for (int m = 0; m < 8; ++m) {
#pragma unroll
    for (int n = 0; n < 4; ++n) {
      f32x4 v = acc[m][n];
      long base = (long)(crow + m * 16) * Ndim + (ccol + n * 16);
      C[base] = v[0];
      C[base + Ndim] = v[1];
      C[base + 2 * (long)Ndim] = v[2];
      C[base + 3 * (long)Ndim] = v[3];
    }
  }
}

extern "C" void kernel_launch(void* const* d_in, const int* in_sizes, int n_in,
                              void* d_out, int out_size, void* d_ws,
                              size_t ws_size, hipStream_t stream) {
  const float* x = (const float*)d_in[0];       // [4,4096,4096] -> [M,K]
  const float* W = (const float*)d_in[1];       // [N,K]
  const float* lA = (const float*)d_in[2];      // [R,K]
  const float* lB = (const float*)d_in[3];      // [N,R]
  float* out = (float*)d_out;                   // [M,N] f32

  ushort* xb = (ushort*)d_ws;                          // M*K bf16 = 134 MB
  ushort* weff = xb + (size_t)Mdim * Kdim;             // N*K bf16 = 33.5 MB

  cast_x_kernel<<<2048, 256, 0, stream>>>((const float4*)x, (ushort4*)xb,
                                          (Mdim * Kdim) / 4);
  make_weff_kernel<<<(Ndim * (Kdim / 8)) / 256, 256, 0, stream>>>(W, lA, lB,
                                                                  weff);
  dim3 grid((Mdim / BM) * (Ndim / BN));  // 64*16 = 1024 blocks
  gemm256<<<grid, 512, 0, stream>>>((const bf16*)xb, (const bf16*)weff, out);
}